// Round 14
// baseline (196.679 us; speedup 1.0000x reference)
//
#include <hip/hip_runtime.h>
#include <cstdint>
#include <cstddef>

// ---------------------------------------------------------------------------
// HierarchicalSparseAttention  B=2 L=4096 D=1024 H=16 DH=64
// cvt(weights only) -> QKV GEMM reading f32 activations via async LDS staging
// (f32->bf16 at fragment build; tree levels 1..6 fused in epilogue) ->
// sparse attn (levels 7..11 computed in-block from level 6) -> output GEMM
// ---------------------------------------------------------------------------

typedef __bf16 bf16;
typedef __bf16 bf16x8 __attribute__((ext_vector_type(8)));
typedef float  f32x4  __attribute__((ext_vector_type(4)));

#define L_SEQ  4096
#define NFLAT  8192   /* padded 2L-1 = 8191 */

__device__ __forceinline__ int off_l(int l) { return 8192 - (8192 >> l); }

// ---- async global->LDS, 16B per lane; lds base must be wave-uniform --------
__device__ __forceinline__ void glds16(const void* g, void* l) {
  __builtin_amdgcn_global_load_lds(
      (const __attribute__((address_space(1))) unsigned int*)g,
      (__attribute__((address_space(3))) unsigned int*)l, 16, 0, 0);
}

#define MEMFENCE asm volatile("" ::: "memory")
__device__ __forceinline__ void barrier_raw() {
  MEMFENCE; __builtin_amdgcn_s_barrier(); MEMFENCE;
}

// st_16x32 XOR swizzle (involution; permutes 16B chunks, preserves alignment)
__device__ __forceinline__ int swz(int b) { return b ^ (((b >> 9) & 1) << 5); }
// byte addr of (row, col2) in a [R][128B] byte-tile stored as [16][1024B]
// subtiles; col2 in 2-byte units (0..63)
__device__ __forceinline__ int la(int row, int col) {
  return ((((row >> 4) << 1) + (col >> 5)) << 10) + ((row & 15) << 6) + ((col & 31) << 1);
}

// ---------------------------------------------------------------------------
// fp32 -> bf16 for the 4 weight matrices only. grid 256 x 256, grid-stride.
// ---------------------------------------------------------------------------
__global__ __launch_bounds__(256) void cvtw_kernel(
    const float* __restrict__ wq, const float* __restrict__ wk,
    const float* __restrict__ wv, const float* __restrict__ wo,
    bf16* __restrict__ wqx, bf16* __restrict__ wkx, bf16* __restrict__ wvx,
    bf16* __restrict__ wox) {
  for (int i = blockIdx.x * 256 + threadIdx.x; i < 524288; i += 65536) {
    const int t = i >> 17; const int g = i & 131071;
    const float* s = (t == 0) ? wq : (t == 1) ? wk : (t == 2) ? wv : wo;
    bf16*        d = (t == 0) ? wqx : (t == 1) ? wkx : (t == 2) ? wvx : wox;
    const float4 v0 = ((const float4*)s)[(size_t)g * 2];
    const float4 v1 = ((const float4*)s)[(size_t)g * 2 + 1];
    bf16x8 o;
    o[0] = (bf16)v0.x; o[1] = (bf16)v0.y; o[2] = (bf16)v0.z; o[3] = (bf16)v0.w;
    o[4] = (bf16)v1.x; o[5] = (bf16)v1.y; o[6] = (bf16)v1.z; o[7] = (bf16)v1.w;
    *(bf16x8*)(d + (size_t)g * 8) = o;
  }
}

// ---------------------------------------------------------------------------
// QKV GEMM: C(128x128) = A_f32(128xK) * W_bf16(128xK)^T, K=1024.
// A staged as raw f32 bytes (BK=32 tiles, 16KB); W staged bf16 (BK=64 tiles,
// 16KB). Both 2-ring, depth-1 prefetch, vmcnt(0)+barrier per step (R10-exact,
// best-measured 155.2 us e2e). f32->bf16 at fragment build (RNE).
// 256 thr = 4 waves (2x2); wave 64x64 = 4x4 frags of 16x16x32.
// ---------------------------------------------------------------------------
__device__ __forceinline__ void stage_A32(const float* __restrict__ A,
                                          int tm, int k0, char* buf,
                                          int tid, int wid) {
#pragma unroll
  for (int i = 0; i < 4; i++) {
    const int d  = i * 4096 + tid * 16;
    const int lb = swz(d);
    const int row = ((lb >> 10) >> 1) * 16 + ((lb >> 6) & 15);
    const int col = ((lb >> 10) & 1) * 16 + ((lb & 63) >> 2);   // f32 col
    glds16(A + (size_t)(tm * 128 + row) * 1024 + k0 + col,
           buf + i * 4096 + wid * 1024);
  }
}
__device__ __forceinline__ void stage_B64(const bf16* __restrict__ W,
                                          int tn, int k0, char* buf,
                                          int tid, int wid) {
#pragma unroll
  for (int i = 0; i < 4; i++) {
    const int d  = i * 4096 + tid * 16;
    const int lb = swz(d);
    const int row = ((lb >> 10) >> 1) * 16 + ((lb >> 6) & 15);
    const int col = ((lb >> 10) & 1) * 32 + ((lb & 63) >> 1);   // bf16 col
    glds16(W + (size_t)(tn * 128 + row) * 1024 + k0 + col,
           buf + i * 4096 + wid * 1024);
  }
}

__device__ __forceinline__ void gemmf_core(const float* __restrict__ A,
                                           const bf16* __restrict__ W,
                                           int tm, int tn, char* lds,
                                           f32x4 (&acc)[4][4]) {
  const int tid  = threadIdx.x;
  const int wid  = tid >> 6, lane = tid & 63;
  const int wm   = wid >> 1, wn = wid & 1;
  const int laneR  = lane & 15;
  const int k16    = lane >> 4;          // 0..3
  char* Al = lds;                        // 2 x 16KB
  char* Bl = lds + 32768;                // 2 x 16KB

  stage_A32(A, tm, 0, Al, tid, wid);
  stage_B64(W, tn, 0, Bl, tid, wid);

  for (int s = 0; s < 32; ++s) {
    asm volatile("s_waitcnt vmcnt(0)" ::: "memory");
    barrier_raw();   // stage(s) visible; buffers for s+1 fully consumed
    if (s + 1 < 32) stage_A32(A, tm, (s + 1) << 5, Al + ((s + 1) & 1) * 16384, tid, wid);
    if (!(s & 1) && (s >> 1) + 1 < 16)
      stage_B64(W, tn, ((s >> 1) + 1) << 6, Bl + (((s >> 1) + 1) & 1) * 16384, tid, wid);

    const char* Ab = Al + (s & 1) * 16384;
    const char* Bb = Bl + ((s >> 1) & 1) * 16384;
    const int kc = (s & 1) * 32;         // bf16 col-half within B tile

    bf16x8 af[4], bfr[4];
#pragma unroll
    for (int f = 0; f < 4; f++) {
      const int row = wm * 64 + f * 16 + laneR;
      const f32x4 a0 = *(const f32x4*)(Ab + swz(la(row, k16 * 16)));
      const f32x4 a1 = *(const f32x4*)(Ab + swz(la(row, k16 * 16 + 8)));
      bf16x8 o;
      o[0] = (bf16)a0[0]; o[1] = (bf16)a0[1]; o[2] = (bf16)a0[2]; o[3] = (bf16)a0[3];
      o[4] = (bf16)a1[0]; o[5] = (bf16)a1[1]; o[6] = (bf16)a1[2]; o[7] = (bf16)a1[3];
      af[f] = o;
    }
#pragma unroll
    for (int j = 0; j < 4; j++) {
      const int row = wn * 64 + j * 16 + laneR;
      bfr[j] = *(const bf16x8*)(Bb + swz(la(row, kc + k16 * 8)));
    }

    __builtin_amdgcn_s_setprio(1);
#pragma unroll
    for (int f = 0; f < 4; f++)
#pragma unroll
      for (int j = 0; j < 4; j++)
        acc[f][j] = __builtin_amdgcn_mfma_f32_16x16x32_bf16(af[f], bfr[j], acc[f][j], 0, 0, 0);
    __builtin_amdgcn_s_setprio(0);
  }
}

// XCD-chunked bijective tile map (512 blocks/z, xcd=bid&7): XCD x owns tm in
// [8x,8x+8) for all tn -> per-XCD A working set L2-resident.
__device__ __forceinline__ void tile_map(int bid, int& tm, int& tn) {
  const int xcd = bid & 7, q = bid >> 3;
  tm = xcd * 8 + (q >> 3);
  tn = q & 7;
}

// QKV projections + fused K/V tree levels 1..6. grid = (512, 3).
__global__ __launch_bounds__(256, 2) void gemmf_qkv_kernel(
    const float* __restrict__ qf, const float* __restrict__ kf, const float* __restrict__ vf,
    const bf16* __restrict__ wq, const bf16* __restrict__ wk, const bf16* __restrict__ wv,
    bf16* __restrict__ Qb, bf16* __restrict__ fK, bf16* __restrict__ fV) {
  __shared__ __align__(16) char lds[65536];
  const int z = blockIdx.y;
  const float* A = (z == 0) ? qf : (z == 1) ? kf : vf;
  const bf16*  W = (z == 0) ? wq : (z == 1) ? wk : wv;
  bf16* D        = (z == 0) ? Qb : (z == 1) ? fK : fV;
  const int lstr = (z == 0) ? L_SEQ : NFLAT;
  int tm, tn; tile_map(blockIdx.x, tm, tn);
  f32x4 acc[4][4] = {};
  gemmf_core(A, W, tm, tn, lds, acc);

  const int lane = threadIdx.x & 63, wid = threadIdx.x >> 6;
  const int rl0 = (wid >> 1) * 64 + (lane >> 4) * 4;   // local row
  const int cl0 = (wid & 1) * 64 + (lane & 15);        // local col
#pragma unroll
  for (int i = 0; i < 4; i++)
#pragma unroll
    for (int j = 0; j < 4; j++)
#pragma unroll
      for (int r = 0; r < 4; r++) {
        const int m = tm * 128 + rl0 + i * 16 + r;
        const int n = tn * 128 + cl0 + j * 16;
        const int b = m >> 12, l = m & 4095;
        const int h = n >> 6,  dh = n & 63;
        D[((size_t)(b * 16 + h) * lstr + l) * 64 + dh] = (bf16)acc[i][j][r];
      }

  // ---- fused tree levels 1..6 (K and V blocks only) ----
  if (z != 0) {
    bf16* Ct = (bf16*)lds;                 // [128][132] bf16 = 33792B (<64KB)
    barrier_raw();                         // all waves done reading ring bufs
#pragma unroll
    for (int i = 0; i < 4; i++)
#pragma unroll
      for (int j = 0; j < 4; j++)
#pragma unroll
        for (int r = 0; r < 4; r++)
          Ct[(rl0 + i * 16 + r) * 132 + (cl0 + j * 16)] = (bf16)acc[i][j][r];
    barrier_raw();

    const int g2 = threadIdx.x >> 7;       // 64-leaf group within tile
    const int c  = threadIdx.x & 127;      // local col
    const int h  = tn * 2 + (c >> 6), dh = c & 63;
    const int b  = (tm * 128) >> 12;
    const int lbase = ((tm * 128) & 4095) + g2 * 64;
    const size_t fb = (size_t)(b * 16 + h) * NFLAT * 64 + dh;
    float pk[7];
#pragma unroll
    for (int i = 0; i < 64; i++) {
      float ck = (float)Ct[(g2 * 64 + i) * 132 + c];
#pragma unroll
      for (int l = 1; l <= 6; l++) {
        if (((i + 1) & ((1 << l) - 1)) != 0) { pk[l] = ck; break; }
        ck += pk[l];
        const int j = (lbase + i) >> l;
        D[fb + (size_t)(off_l(l) + j) * 64] =
            (bf16)(z == 1 ? ck * (1.0f / (1 << l)) : ck);
      }
    }
  }
}

// ---------------------------------------------------------------------------
// Output GEMM (bf16 A via global_load_lds, R7 core) + bias, f32 out.
// ---------------------------------------------------------------------------
#define BUFB 32768   /* 16KB A + 16KB B */

__device__ __forceinline__ void stage_tile(const bf16* __restrict__ A,
                                           const bf16* __restrict__ W,
                                           int tm, int tn, int k0,
                                           char* buf, int tid, int wid) {
  bf16* Ad = (bf16*)buf;
  bf16* Bd = (bf16*)(buf + 16384);
#pragma unroll
  for (int i = 0; i < 4; i++) {
    const int d  = i * 4096 + tid * 16;
    const int lb = swz(d);
    const int row = ((lb >> 10) >> 1) * 16 + ((lb >> 6) & 15);
    const int col = ((lb >> 10) & 1) * 32 + ((lb & 63) >> 1);
    glds16(A + (size_t)(tm * 128 + row) * 1024 + k0 + col, Ad + ((i * 4096 + wid * 1024) >> 1));
    glds16(W + (size_t)(tn * 128 + row) * 1024 + k0 + col, Bd + ((i * 4096 + wid * 1024) >> 1));
  }
}

__device__ __forceinline__ void gemm8_core(const bf16* __restrict__ A,
                                           const bf16* __restrict__ W,
                                           int tm, int tn, char* lds,
                                           f32x4 (&acc)[4][4]) {
  const int tid  = threadIdx.x;
  const int wid  = tid >> 6, lane = tid & 63;
  const int wm   = wid >> 1, wn = wid & 1;
  const int laneR  = lane & 15;
  const int laneC8 = (lane >> 4) * 8;

  stage_tile(A, W, tm, tn, 0, lds, tid, wid);

  for (int u = 0; u < 16; ++u) {
    asm volatile("s_waitcnt vmcnt(0)" ::: "memory");
    barrier_raw();
    if (u + 1 < 16)
      stage_tile(A, W, tm, tn, (u + 1) << 6, lds + ((u + 1) & 1) * BUFB, tid, wid);

    const char* Ab = lds + (u & 1) * BUFB;
    const char* Bb = Ab + 16384;
    bf16x8 af[4][2], bfr[4][2];
#pragma unroll
    for (int f = 0; f < 4; f++)
#pragma unroll
      for (int ks = 0; ks < 2; ks++)
        af[f][ks] = *(const bf16x8*)(Ab + swz(la(wm * 64 + f * 16 + laneR, ks * 32 + laneC8)));
#pragma unroll
    for (int j = 0; j < 4; j++)
#pragma unroll
      for (int ks = 0; ks < 2; ks++)
        bfr[j][ks] = *(const bf16x8*)(Bb + swz(la(wn * 64 + j * 16 + laneR, ks * 32 + laneC8)));

    __builtin_amdgcn_s_setprio(1);
#pragma unroll
    for (int f = 0; f < 4; f++)
#pragma unroll
      for (int j = 0; j < 4; j++)
#pragma unroll
        for (int ks = 0; ks < 2; ks++)
          acc[f][j] = __builtin_amdgcn_mfma_f32_16x16x32_bf16(
              af[f][ks], bfr[j][ks], acc[f][j], 0, 0, 0);
    __builtin_amdgcn_s_setprio(0);
  }
}

__global__ __launch_bounds__(256, 2) void gemm8_out_kernel(
    const bf16* __restrict__ Ob, const bf16* __restrict__ wo,
    const float* __restrict__ bo, float* __restrict__ out) {
  __shared__ __align__(16) char lds[2 * BUFB];
  int tm, tn; tile_map(blockIdx.x, tm, tn);
  f32x4 acc[4][4] = {};
  gemm8_core(Ob, wo, tm, tn, lds, acc);
  const int lane = threadIdx.x & 63, wid = threadIdx.x >> 6;
  const int m0 = tm * 128 + (wid >> 1) * 64 + (lane >> 4) * 4;
  const int n0 = tn * 128 + (wid & 1) * 64 + (lane & 15);
#pragma unroll
  for (int i = 0; i < 4; i++)
#pragma unroll
    for (int j = 0; j < 4; j++)
#pragma unroll
      for (int r = 0; r < 4; r++) {
        const int m = m0 + i * 16 + r;
        const int n = n0 + j * 16;
        out[(size_t)m * 1024 + n] = acc[i][j][r] + bo[n];
      }
}

// ---------------------------------------------------------------------------
// Sparse attention. Block = 1 wave = 64 tokens of one (b,h).
// LDS rows 0..62: staged levels 1..6 (63 rows). Rows 63..67: levels 7..11
// COMPUTED in-block from level-6 nodes (disjoint sibling subtrees, 62 rows,
// L2-resident) -- replaces the former tree_l712 kernel. Level-0 rows (self
// and tid^1) read direct from global. grid = (64, 32)
// ---------------------------------------------------------------------------
__global__ __launch_bounds__(64) void attn_kernel(
    const bf16* __restrict__ Qb, const bf16* __restrict__ fK,
    const bf16* __restrict__ fV, bf16* __restrict__ Ob) {
  __shared__ __align__(16) unsigned short Kl[68 * 64];
  __shared__ __align__(16) unsigned short Vl[68 * 64];
  const int t0  = blockIdx.x * 64;
  const int bh  = blockIdx.y;
  const int tid = threadIdx.x;
  const size_t fb = (size_t)bh * NFLAT * 64;

  // --- stage 63 tree rows (levels 1..6), XOR-swizzled chunks ---
  for (int u = tid; u < 63 * 8; u += 64) {
    const int r = u >> 3, c = u & 7;
    int flat;
    if      (r < 32) flat = 4096 + (t0 >> 1) + r;         // level 1
    else if (r < 48) flat = 6144 + (t0 >> 2) + (r - 32);  // level 2
    else if (r < 56) flat = 7168 + (t0 >> 3) + (r - 48);  // level 3
    else if (r < 60) flat = 7680 + (t0 >> 4) + (r - 56);  // level 4
    else if (r < 62) flat = 7936 + (t0 >> 5) + (r - 60);  // level 5
    else             flat = (8064 + (t0 >> 6)) ^ 1;       // level 6 (r==62)
    const int cc = c ^ (r & 7);
    const uint4 kk = *(const uint4*)((const char*)(fK + fb + (size_t)flat * 64) + c * 16);
    const uint4 vv = *(const uint4*)((const char*)(fV + fb + (size_t)flat * 64) + c * 16);
    *(uint4*)((char*)Kl + r * 128 + cc * 16) = kk;
    *(uint4*)((char*)Vl + r * 128 + cc * 16) = vv;
  }
  // --- compute rows 63..67 (levels 7..11) from level-6 nodes; lane = col ---
  {
    const int d = tid;
    const bf16* K6 = fK + fb + (size_t)8064 * 64 + d;   // off_l(6)=8064
    const bf16* V6 = fV + fb + (size_t)8064 * 64 + d;
#pragma unroll
    for (int l = 7; l <= 11; l++) {
      const int cnt  = 1 << (l - 6);
      const int base = ((t0 >> l) ^ 1) << (l - 6);      // sibling's lvl-6 span
      float ka = 0.f, va = 0.f;
#pragma unroll
      for (int i = 0; i < (1 << (11 - 6)); i++) {       // bound 32; guard below
        if (i < cnt) {
          ka += (float)K6[(size_t)(base + i) * 64];
          va += (float)V6[(size_t)(base + i) * 64];
        }
      }
      const int r = 56 + l;                             // 63..67
      const int byte = r * 128 + (((d >> 3) ^ (r & 7)) << 4) + ((d & 7) << 1);
      *(bf16*)((char*)Kl + byte) = (bf16)(ka * (1.0f / cnt));
      *(bf16*)((char*)Vl + byte) = (bf16)va;
    }
  }
  __syncthreads();

  const int n = t0 + tid;
  int rows[13];
#pragma unroll
  for (int l = 1; l < 12; l++) {
    int r;
    if (l <= 5) r = (64 - (128 >> l)) + (((n >> l) ^ 1) - (t0 >> l));
    else        r = 62 + (l - 6);
    rows[l + 1] = r;
  }

  float q[64];
  const bf16* Qr = Qb + ((size_t)bh * L_SEQ + n) * 64;
#pragma unroll
  for (int c = 0; c < 8; c++) {
    bf16x8 v = *(const bf16x8*)(Qr + c * 8);
#pragma unroll
    for (int j = 0; j < 8; j++) q[c * 8 + j] = (float)v[j];
  }

  float lg[13];
  {
    const bf16* Ks0 = fK + fb + (size_t)(t0 + tid) * 64;
    const bf16* Kn0 = fK + fb + (size_t)(t0 + (tid ^ 1)) * 64;
    float a0 = 0.f, a1 = 0.f;
#pragma unroll
    for (int c = 0; c < 8; c++) {
      const bf16x8 s = *(const bf16x8*)(Ks0 + c * 8);
      const bf16x8 t = *(const bf16x8*)(Kn0 + c * 8);
#pragma unroll
      for (int j = 0; j < 8; j++) { a0 += q[c * 8 + j] * (float)s[j]; a1 += q[c * 8 + j] * (float)t[j]; }
    }
    lg[0] = a0 * 0.125f; lg[1] = a1 * 0.125f;
  }
#pragma unroll
  for (int v = 2; v < 13; v++) {
    const int r = rows[v];
    float a = 0.f;
#pragma unroll
    for (int c = 0; c < 8; c++) {
      const int cc = c ^ (r & 7);
      const bf16x8 kv = *(const bf16x8*)((const char*)Kl + r * 128 + cc * 16);
#pragma unroll
      for (int j = 0; j < 8; j++) a += q[c * 8 + j] * (float)kv[j];
    }
    lg[v] = a * 0.125f;
  }
#pragma unroll
  for (int v = 1; v < 13; v++)
    if (!((n >> (v - 1)) & 1)) lg[v] = -1e30f;

  float mx = lg[0];
#pragma unroll
  for (int v = 1; v < 13; v++) mx = fmaxf(mx, lg[v]);
  float w[13], s = 0.f;
#pragma unroll
  for (int v = 0; v < 13; v++) { w[v] = __expf(lg[v] - mx); s += w[v]; }
  const float inv = 1.0f / s;

  float o[64];
#pragma unroll
  for (int d = 0; d < 64; d++) o[d] = 0.f;
  {
    const bf16* Vs0 = fV + fb + (size_t)(t0 + tid) * 64;
    const bf16* Vn0 = fV + fb + (size_t)(t0 + (tid ^ 1)) * 64;
    const float w0 = w[0], w1 = w[1];
#pragma unroll
    for (int c = 0; c < 8; c++) {
      const bf16x8 s0 = *(const bf16x8*)(Vs0 + c * 8);
      const bf16x8 t1 = *(const bf16x8*)(Vn0 + c * 8);
#pragma unroll
      for (int j = 0; j < 8; j++) o[c * 8 + j] += w0 * (float)s0[j] + w1 * (float)t1[j];
    }
  }
#pragma unroll
  for (int v = 2; v < 13; v++) {
    const int r = rows[v];
    const float wv = w[v];
#pragma unroll
    for (int c = 0; c < 8; c++) {
      const int cc = c ^ (r & 7);
      const bf16x8 vv = *(const bf16x8*)((const char*)Vl + r * 128 + cc * 16);
#pragma unroll
      for (int j = 0; j < 8; j++) o[c * 8 + j] += wv * (float)vv[j];
    }
  }

  bf16* Or = Ob + ((size_t)(bh >> 4) * L_SEQ + n) * 1024 + (size_t)(bh & 15) * 64;
#pragma unroll
  for (int c = 0; c < 8; c++) {
    bf16x8 ov;
#pragma unroll
    for (int j = 0; j < 8; j++) ov[j] = (bf16)(o[c * 8 + j] * inv);
    *(bf16x8*)(Or + c * 8) = ov;
  }
}

// ---------------------------------------------------------------------------
extern "C" void kernel_launch(void* const* d_in, const int* in_sizes, int n_in,
                              void* d_out, int out_size, void* d_ws, size_t ws_size,
                              hipStream_t stream) {
  const float* query = (const float*)d_in[0];
  const float* key   = (const float*)d_in[1];
  const float* value = (const float*)d_in[2];
  const float* Wq    = (const float*)d_in[3];
  const float* Wk    = (const float*)d_in[4];
  const float* Wv    = (const float*)d_in[5];
  const float* Wo    = (const float*)d_in[6];
  const float* bo    = (const float*)d_in[7];
  float* out = (float*)d_out;

  char* ws = (char*)d_ws;
  size_t off = 0;
  auto take = [&](size_t bytes) -> void* {
    void* p = ws + off;
    off += (bytes + 255) & ~(size_t)255;
    return p;
  };
  const size_t WB = (size_t)1024 * 1024 * 2;   // 2.10 MB
  bf16* wqx = (bf16*)take(WB);
  bf16* wkx = (bf16*)take(WB);
  bf16* wvx = (bf16*)take(WB);
  bf16* wox = (bf16*)take(WB);
  bf16* Qb  = (bf16*)take((size_t)32 * L_SEQ * 64 * 2);   // 16.78 MB
  bf16* fK  = (bf16*)take((size_t)32 * NFLAT * 64 * 2);   // 33.55 MB
  bf16* fV  = (bf16*)take((size_t)32 * NFLAT * 64 * 2);   // 33.55 MB
  bf16* Ob  = (bf16*)take((size_t)8192 * 1024 * 2);       // 16.78 MB
  (void)in_sizes; (void)n_in; (void)out_size; (void)ws_size;

  // 1. weights fp32 -> bf16
  cvtw_kernel<<<256, 256, 0, stream>>>(Wq, Wk, Wv, Wo, wqx, wkx, wvx, wox);

  // 2. Q/K/V projections reading f32 activations directly + tree levels 1..6
  gemmf_qkv_kernel<<<dim3(512, 3), 256, 0, stream>>>(
      query, key, value, wqx, wkx, wvx, Qb, fK, fV);

  // 3. sparse attention (computes levels 7..11 in-block)
  attn_kernel<<<dim3(64, 32), 64, 0, stream>>>(Qb, fK, fV, Ob);

  // 4. output projection
  gemm8_out_kernel<<<512, 256, 0, stream>>>(Ob, wox, bo, out);
}

// Round 15
// 155.051 us; speedup vs baseline: 1.2685x; 1.2685x over previous
//
#include <hip/hip_runtime.h>
#include <cstdint>
#include <cstddef>

// ---------------------------------------------------------------------------
// HierarchicalSparseAttention  B=2 L=4096 D=1024 H=16 DH=64
// cvt(weights only) -> QKV GEMM reading f32 activations via async LDS staging
// (f32->bf16 at fragment build; tree levels 1..6 fused in epilogue) ->
// tree_l712 -> sparse attn (68-row staging) -> output GEMM (+bias, f32)
// R10-exact control build (best measured: 155.2 us e2e).
// ---------------------------------------------------------------------------

typedef __bf16 bf16;
typedef __bf16 bf16x8 __attribute__((ext_vector_type(8)));
typedef float  f32x4  __attribute__((ext_vector_type(4)));

#define L_SEQ  4096
#define NFLAT  8192   /* padded 2L-1 = 8191 */

__device__ __forceinline__ int off_l(int l) { return 8192 - (8192 >> l); }

// ---- async global->LDS, 16B per lane; lds base must be wave-uniform --------
__device__ __forceinline__ void glds16(const void* g, void* l) {
  __builtin_amdgcn_global_load_lds(
      (const __attribute__((address_space(1))) unsigned int*)g,
      (__attribute__((address_space(3))) unsigned int*)l, 16, 0, 0);
}

#define MEMFENCE asm volatile("" ::: "memory")
__device__ __forceinline__ void barrier_raw() {
  MEMFENCE; __builtin_amdgcn_s_barrier(); MEMFENCE;
}

// st_16x32 XOR swizzle (involution; permutes 16B chunks, preserves alignment)
__device__ __forceinline__ int swz(int b) { return b ^ (((b >> 9) & 1) << 5); }
// byte addr of (row, col2) in a [R][128B] byte-tile stored as [16][1024B]
// subtiles; col2 in 2-byte units (0..63)
__device__ __forceinline__ int la(int row, int col) {
  return ((((row >> 4) << 1) + (col >> 5)) << 10) + ((row & 15) << 6) + ((col & 31) << 1);
}

// ---------------------------------------------------------------------------
// fp32 -> bf16 for the 4 weight matrices only. grid 256 x 256, grid-stride.
// ---------------------------------------------------------------------------
__global__ __launch_bounds__(256) void cvtw_kernel(
    const float* __restrict__ wq, const float* __restrict__ wk,
    const float* __restrict__ wv, const float* __restrict__ wo,
    bf16* __restrict__ wqx, bf16* __restrict__ wkx, bf16* __restrict__ wvx,
    bf16* __restrict__ wox) {
  for (int i = blockIdx.x * 256 + threadIdx.x; i < 524288; i += 65536) {
    const int t = i >> 17; const int g = i & 131071;
    const float* s = (t == 0) ? wq : (t == 1) ? wk : (t == 2) ? wv : wo;
    bf16*        d = (t == 0) ? wqx : (t == 1) ? wkx : (t == 2) ? wvx : wox;
    const float4 v0 = ((const float4*)s)[(size_t)g * 2];
    const float4 v1 = ((const float4*)s)[(size_t)g * 2 + 1];
    bf16x8 o;
    o[0] = (bf16)v0.x; o[1] = (bf16)v0.y; o[2] = (bf16)v0.z; o[3] = (bf16)v0.w;
    o[4] = (bf16)v1.x; o[5] = (bf16)v1.y; o[6] = (bf16)v1.z; o[7] = (bf16)v1.w;
    *(bf16x8*)(d + (size_t)g * 8) = o;
  }
}

// ---------------------------------------------------------------------------
// QKV GEMM: C(128x128) = A_f32(128xK) * W_bf16(128xK)^T, K=1024.
// A staged as raw f32 bytes (BK=32 tiles, 16KB); W staged bf16 (BK=64 tiles,
// 16KB). Both 2-ring, depth-1 prefetch, vmcnt(0)+barrier per step.
// f32->bf16 at fragment build (RNE). 256 thr = 4 waves (2x2).
// ---------------------------------------------------------------------------
__device__ __forceinline__ void stage_A32(const float* __restrict__ A,
                                          int tm, int k0, char* buf,
                                          int tid, int wid) {
#pragma unroll
  for (int i = 0; i < 4; i++) {
    const int d  = i * 4096 + tid * 16;
    const int lb = swz(d);
    const int row = ((lb >> 10) >> 1) * 16 + ((lb >> 6) & 15);
    const int col = ((lb >> 10) & 1) * 16 + ((lb & 63) >> 2);   // f32 col
    glds16(A + (size_t)(tm * 128 + row) * 1024 + k0 + col,
           buf + i * 4096 + wid * 1024);
  }
}
__device__ __forceinline__ void stage_B64(const bf16* __restrict__ W,
                                          int tn, int k0, char* buf,
                                          int tid, int wid) {
#pragma unroll
  for (int i = 0; i < 4; i++) {
    const int d  = i * 4096 + tid * 16;
    const int lb = swz(d);
    const int row = ((lb >> 10) >> 1) * 16 + ((lb >> 6) & 15);
    const int col = ((lb >> 10) & 1) * 32 + ((lb & 63) >> 1);   // bf16 col
    glds16(W + (size_t)(tn * 128 + row) * 1024 + k0 + col,
           buf + i * 4096 + wid * 1024);
  }
}

__device__ __forceinline__ void gemmf_core(const float* __restrict__ A,
                                           const bf16* __restrict__ W,
                                           int tm, int tn, char* lds,
                                           f32x4 (&acc)[4][4]) {
  const int tid  = threadIdx.x;
  const int wid  = tid >> 6, lane = tid & 63;
  const int wm   = wid >> 1, wn = wid & 1;
  const int laneR  = lane & 15;
  const int k16    = lane >> 4;          // 0..3
  char* Al = lds;                        // 2 x 16KB
  char* Bl = lds + 32768;                // 2 x 16KB

  stage_A32(A, tm, 0, Al, tid, wid);
  stage_B64(W, tn, 0, Bl, tid, wid);

  for (int s = 0; s < 32; ++s) {
    asm volatile("s_waitcnt vmcnt(0)" ::: "memory");
    barrier_raw();   // stage(s) visible; buffers for s+1 fully consumed
    if (s + 1 < 32) stage_A32(A, tm, (s + 1) << 5, Al + ((s + 1) & 1) * 16384, tid, wid);
    if (!(s & 1) && (s >> 1) + 1 < 16)
      stage_B64(W, tn, ((s >> 1) + 1) << 6, Bl + (((s >> 1) + 1) & 1) * 16384, tid, wid);

    const char* Ab = Al + (s & 1) * 16384;
    const char* Bb = Bl + ((s >> 1) & 1) * 16384;
    const int kc = (s & 1) * 32;         // bf16 col-half within B tile

    bf16x8 af[4], bfr[4];
#pragma unroll
    for (int f = 0; f < 4; f++) {
      const int row = wm * 64 + f * 16 + laneR;
      const f32x4 a0 = *(const f32x4*)(Ab + swz(la(row, k16 * 16)));
      const f32x4 a1 = *(const f32x4*)(Ab + swz(la(row, k16 * 16 + 8)));
      bf16x8 o;
      o[0] = (bf16)a0[0]; o[1] = (bf16)a0[1]; o[2] = (bf16)a0[2]; o[3] = (bf16)a0[3];
      o[4] = (bf16)a1[0]; o[5] = (bf16)a1[1]; o[6] = (bf16)a1[2]; o[7] = (bf16)a1[3];
      af[f] = o;
    }
#pragma unroll
    for (int j = 0; j < 4; j++) {
      const int row = wn * 64 + j * 16 + laneR;
      bfr[j] = *(const bf16x8*)(Bb + swz(la(row, kc + k16 * 8)));
    }

    __builtin_amdgcn_s_setprio(1);
#pragma unroll
    for (int f = 0; f < 4; f++)
#pragma unroll
      for (int j = 0; j < 4; j++)
        acc[f][j] = __builtin_amdgcn_mfma_f32_16x16x32_bf16(af[f], bfr[j], acc[f][j], 0, 0, 0);
    __builtin_amdgcn_s_setprio(0);
  }
}

// XCD-chunked bijective tile map (512 blocks/z, xcd=bid&7): XCD x owns tm in
// [8x,8x+8) for all tn -> per-XCD A working set L2-resident.
__device__ __forceinline__ void tile_map(int bid, int& tm, int& tn) {
  const int xcd = bid & 7, q = bid >> 3;
  tm = xcd * 8 + (q >> 3);
  tn = q & 7;
}

// QKV projections + fused K/V tree levels 1..6. grid = (512, 3).
__global__ __launch_bounds__(256, 2) void gemmf_qkv_kernel(
    const float* __restrict__ qf, const float* __restrict__ kf, const float* __restrict__ vf,
    const bf16* __restrict__ wq, const bf16* __restrict__ wk, const bf16* __restrict__ wv,
    bf16* __restrict__ Qb, bf16* __restrict__ fK, bf16* __restrict__ fV) {
  __shared__ __align__(16) char lds[65536];
  const int z = blockIdx.y;
  const float* A = (z == 0) ? qf : (z == 1) ? kf : vf;
  const bf16*  W = (z == 0) ? wq : (z == 1) ? wk : wv;
  bf16* D        = (z == 0) ? Qb : (z == 1) ? fK : fV;
  const int lstr = (z == 0) ? L_SEQ : NFLAT;
  int tm, tn; tile_map(blockIdx.x, tm, tn);
  f32x4 acc[4][4] = {};
  gemmf_core(A, W, tm, tn, lds, acc);

  const int lane = threadIdx.x & 63, wid = threadIdx.x >> 6;
  const int rl0 = (wid >> 1) * 64 + (lane >> 4) * 4;   // local row
  const int cl0 = (wid & 1) * 64 + (lane & 15);        // local col
#pragma unroll
  for (int i = 0; i < 4; i++)
#pragma unroll
    for (int j = 0; j < 4; j++)
#pragma unroll
      for (int r = 0; r < 4; r++) {
        const int m = tm * 128 + rl0 + i * 16 + r;
        const int n = tn * 128 + cl0 + j * 16;
        const int b = m >> 12, l = m & 4095;
        const int h = n >> 6,  dh = n & 63;
        D[((size_t)(b * 16 + h) * lstr + l) * 64 + dh] = (bf16)acc[i][j][r];
      }

  // ---- fused tree levels 1..6 (K and V blocks only) ----
  if (z != 0) {
    bf16* Ct = (bf16*)lds;                 // [128][132] bf16 = 33792B (<64KB)
    barrier_raw();                         // all waves done reading ring bufs
#pragma unroll
    for (int i = 0; i < 4; i++)
#pragma unroll
      for (int j = 0; j < 4; j++)
#pragma unroll
        for (int r = 0; r < 4; r++)
          Ct[(rl0 + i * 16 + r) * 132 + (cl0 + j * 16)] = (bf16)acc[i][j][r];
    barrier_raw();

    const int g2 = threadIdx.x >> 7;       // 64-leaf group within tile
    const int c  = threadIdx.x & 127;      // local col
    const int h  = tn * 2 + (c >> 6), dh = c & 63;
    const int b  = (tm * 128) >> 12;
    const int lbase = ((tm * 128) & 4095) + g2 * 64;
    const size_t fb = (size_t)(b * 16 + h) * NFLAT * 64 + dh;
    float pk[7];
#pragma unroll
    for (int i = 0; i < 64; i++) {
      float ck = (float)Ct[(g2 * 64 + i) * 132 + c];
#pragma unroll
      for (int l = 1; l <= 6; l++) {
        if (((i + 1) & ((1 << l) - 1)) != 0) { pk[l] = ck; break; }
        ck += pk[l];
        const int j = (lbase + i) >> l;
        D[fb + (size_t)(off_l(l) + j) * 64] =
            (bf16)(z == 1 ? ck * (1.0f / (1 << l)) : ck);
      }
    }
  }
}

// ---------------------------------------------------------------------------
// Output GEMM (bf16 A via global_load_lds, R7 core) + bias, f32 out.
// ---------------------------------------------------------------------------
#define BUFB 32768   /* 16KB A + 16KB B */

__device__ __forceinline__ void stage_tile(const bf16* __restrict__ A,
                                           const bf16* __restrict__ W,
                                           int tm, int tn, int k0,
                                           char* buf, int tid, int wid) {
  bf16* Ad = (bf16*)buf;
  bf16* Bd = (bf16*)(buf + 16384);
#pragma unroll
  for (int i = 0; i < 4; i++) {
    const int d  = i * 4096 + tid * 16;
    const int lb = swz(d);
    const int row = ((lb >> 10) >> 1) * 16 + ((lb >> 6) & 15);
    const int col = ((lb >> 10) & 1) * 32 + ((lb & 63) >> 1);
    glds16(A + (size_t)(tm * 128 + row) * 1024 + k0 + col, Ad + ((i * 4096 + wid * 1024) >> 1));
    glds16(W + (size_t)(tn * 128 + row) * 1024 + k0 + col, Bd + ((i * 4096 + wid * 1024) >> 1));
  }
}

__device__ __forceinline__ void gemm8_core(const bf16* __restrict__ A,
                                           const bf16* __restrict__ W,
                                           int tm, int tn, char* lds,
                                           f32x4 (&acc)[4][4]) {
  const int tid  = threadIdx.x;
  const int wid  = tid >> 6, lane = tid & 63;
  const int wm   = wid >> 1, wn = wid & 1;
  const int laneR  = lane & 15;
  const int laneC8 = (lane >> 4) * 8;

  stage_tile(A, W, tm, tn, 0, lds, tid, wid);

  for (int u = 0; u < 16; ++u) {
    asm volatile("s_waitcnt vmcnt(0)" ::: "memory");
    barrier_raw();
    if (u + 1 < 16)
      stage_tile(A, W, tm, tn, (u + 1) << 6, lds + ((u + 1) & 1) * BUFB, tid, wid);

    const char* Ab = lds + (u & 1) * BUFB;
    const char* Bb = Ab + 16384;
    bf16x8 af[4][2], bfr[4][2];
#pragma unroll
    for (int f = 0; f < 4; f++)
#pragma unroll
      for (int ks = 0; ks < 2; ks++)
        af[f][ks] = *(const bf16x8*)(Ab + swz(la(wm * 64 + f * 16 + laneR, ks * 32 + laneC8)));
#pragma unroll
    for (int j = 0; j < 4; j++)
#pragma unroll
      for (int ks = 0; ks < 2; ks++)
        bfr[j][ks] = *(const bf16x8*)(Bb + swz(la(wn * 64 + j * 16 + laneR, ks * 32 + laneC8)));

    __builtin_amdgcn_s_setprio(1);
#pragma unroll
    for (int f = 0; f < 4; f++)
#pragma unroll
      for (int j = 0; j < 4; j++)
#pragma unroll
        for (int ks = 0; ks < 2; ks++)
          acc[f][j] = __builtin_amdgcn_mfma_f32_16x16x32_bf16(
              af[f][ks], bfr[j][ks], acc[f][j], 0, 0, 0);
    __builtin_amdgcn_s_setprio(0);
  }
}

__global__ __launch_bounds__(256, 2) void gemm8_out_kernel(
    const bf16* __restrict__ Ob, const bf16* __restrict__ wo,
    const float* __restrict__ bo, float* __restrict__ out) {
  __shared__ __align__(16) char lds[2 * BUFB];
  int tm, tn; tile_map(blockIdx.x, tm, tn);
  f32x4 acc[4][4] = {};
  gemm8_core(Ob, wo, tm, tn, lds, acc);
  const int lane = threadIdx.x & 63, wid = threadIdx.x >> 6;
  const int m0 = tm * 128 + (wid >> 1) * 64 + (lane >> 4) * 4;
  const int n0 = tn * 128 + (wid & 1) * 64 + (lane & 15);
#pragma unroll
  for (int i = 0; i < 4; i++)
#pragma unroll
    for (int j = 0; j < 4; j++)
#pragma unroll
      for (int r = 0; r < 4; r++) {
        const int m = m0 + i * 16 + r;
        const int n = n0 + j * 16;
        out[(size_t)m * 1024 + n] = acc[i][j][r] + bo[n];
      }
}

// ---------------------------------------------------------------------------
// Tree levels 7..12 from level 6. Block = 1 wave per bh, lane = column d.
// grid = 32
// ---------------------------------------------------------------------------
__global__ __launch_bounds__(64) void tree_l712(bf16* __restrict__ fK, bf16* __restrict__ fV) {
  __shared__ float Ks[64 * 64];
  __shared__ float Vs[64 * 64];
  const int bh = blockIdx.x, d = threadIdx.x;
  const size_t fb = (size_t)bh * NFLAT * 64;
#pragma unroll 8
  for (int i = 0; i < 64; i++) {
    Ks[i * 64 + d] = (float)fK[fb + (size_t)(8064 + i) * 64 + d];  // off_l(6)=8064
    Vs[i * 64 + d] = (float)fV[fb + (size_t)(8064 + i) * 64 + d];
  }
#pragma unroll
  for (int l = 7; l <= 12; l++) {
    const int cnt = 4096 >> l;
    for (int j = 0; j < cnt; j++) {
      const float k = (Ks[(2 * j) * 64 + d] + Ks[(2 * j + 1) * 64 + d]) * 0.5f;
      const float v =  Vs[(2 * j) * 64 + d] + Vs[(2 * j + 1) * 64 + d];
      Ks[j * 64 + d] = k;
      Vs[j * 64 + d] = v;
      fK[fb + (size_t)(off_l(l) + j) * 64 + d] = (bf16)k;
      fV[fb + (size_t)(off_l(l) + j) * 64 + d] = (bf16)v;
    }
  }
}

// ---------------------------------------------------------------------------
// Sparse attention: 68 shared tree rows (levels 1..11) in LDS, level-0 rows
// direct from global. grid = (64, 32)
// ---------------------------------------------------------------------------
__global__ __launch_bounds__(64) void attn_kernel(
    const bf16* __restrict__ Qb, const bf16* __restrict__ fK,
    const bf16* __restrict__ fV, bf16* __restrict__ Ob) {
  __shared__ __align__(16) unsigned short Kl[68 * 64];
  __shared__ __align__(16) unsigned short Vl[68 * 64];
  const int t0  = blockIdx.x * 64;
  const int bh  = blockIdx.y;
  const int tid = threadIdx.x;
  const size_t fb = (size_t)bh * NFLAT * 64;

  for (int u = tid; u < 68 * 8; u += 64) {
    const int r = u >> 3, c = u & 7;
    int flat;
    if      (r < 32) flat = 4096 + (t0 >> 1) + r;
    else if (r < 48) flat = 6144 + (t0 >> 2) + (r - 32);
    else if (r < 56) flat = 7168 + (t0 >> 3) + (r - 48);
    else if (r < 60) flat = 7680 + (t0 >> 4) + (r - 56);
    else if (r < 62) flat = 7936 + (t0 >> 5) + (r - 60);
    else { const int l = r - 56; flat = (8192 - (8192 >> l) + (t0 >> l)) ^ 1; }
    const int cc = c ^ (r & 7);
    const uint4 kk = *(const uint4*)((const char*)(fK + fb + (size_t)flat * 64) + c * 16);
    const uint4 vv = *(const uint4*)((const char*)(fV + fb + (size_t)flat * 64) + c * 16);
    *(uint4*)((char*)Kl + r * 128 + cc * 16) = kk;
    *(uint4*)((char*)Vl + r * 128 + cc * 16) = vv;
  }
  __syncthreads();

  const int n = t0 + tid;
  int rows[13];
#pragma unroll
  for (int l = 1; l < 12; l++) {
    int r;
    if (l <= 5) r = (64 - (128 >> l)) + (((n >> l) ^ 1) - (t0 >> l));
    else        r = 62 + (l - 6);
    rows[l + 1] = r;
  }

  float q[64];
  const bf16* Qr = Qb + ((size_t)bh * L_SEQ + n) * 64;
#pragma unroll
  for (int c = 0; c < 8; c++) {
    bf16x8 v = *(const bf16x8*)(Qr + c * 8);
#pragma unroll
    for (int j = 0; j < 8; j++) q[c * 8 + j] = (float)v[j];
  }

  float lg[13];
  {
    const bf16* Ks0 = fK + fb + (size_t)(t0 + tid) * 64;
    const bf16* Kn0 = fK + fb + (size_t)(t0 + (tid ^ 1)) * 64;
    float a0 = 0.f, a1 = 0.f;
#pragma unroll
    for (int c = 0; c < 8; c++) {
      const bf16x8 s = *(const bf16x8*)(Ks0 + c * 8);
      const bf16x8 t = *(const bf16x8*)(Kn0 + c * 8);
#pragma unroll
      for (int j = 0; j < 8; j++) { a0 += q[c * 8 + j] * (float)s[j]; a1 += q[c * 8 + j] * (float)t[j]; }
    }
    lg[0] = a0 * 0.125f; lg[1] = a1 * 0.125f;
  }
#pragma unroll
  for (int v = 2; v < 13; v++) {
    const int r = rows[v];
    float a = 0.f;
#pragma unroll
    for (int c = 0; c < 8; c++) {
      const int cc = c ^ (r & 7);
      const bf16x8 kv = *(const bf16x8*)((const char*)Kl + r * 128 + cc * 16);
#pragma unroll
      for (int j = 0; j < 8; j++) a += q[c * 8 + j] * (float)kv[j];
    }
    lg[v] = a * 0.125f;
  }
#pragma unroll
  for (int v = 1; v < 13; v++)
    if (!((n >> (v - 1)) & 1)) lg[v] = -1e30f;

  float mx = lg[0];
#pragma unroll
  for (int v = 1; v < 13; v++) mx = fmaxf(mx, lg[v]);
  float w[13], s = 0.f;
#pragma unroll
  for (int v = 0; v < 13; v++) { w[v] = __expf(lg[v] - mx); s += w[v]; }
  const float inv = 1.0f / s;

  float o[64];
#pragma unroll
  for (int d = 0; d < 64; d++) o[d] = 0.f;
  {
    const bf16* Vs0 = fV + fb + (size_t)(t0 + tid) * 64;
    const bf16* Vn0 = fV + fb + (size_t)(t0 + (tid ^ 1)) * 64;
    const float w0 = w[0], w1 = w[1];
#pragma unroll
    for (int c = 0; c < 8; c++) {
      const bf16x8 s0 = *(const bf16x8*)(Vs0 + c * 8);
      const bf16x8 t1 = *(const bf16x8*)(Vn0 + c * 8);
#pragma unroll
      for (int j = 0; j < 8; j++) o[c * 8 + j] += w0 * (float)s0[j] + w1 * (float)t1[j];
    }
  }
#pragma unroll
  for (int v = 2; v < 13; v++) {
    const int r = rows[v];
    const float wv = w[v];
#pragma unroll
    for (int c = 0; c < 8; c++) {
      const int cc = c ^ (r & 7);
      const bf16x8 vv = *(const bf16x8*)((const char*)Vl + r * 128 + cc * 16);
#pragma unroll
      for (int j = 0; j < 8; j++) o[c * 8 + j] += wv * (float)vv[j];
    }
  }

  bf16* Or = Ob + ((size_t)(bh >> 4) * L_SEQ + n) * 1024 + (size_t)(bh & 15) * 64;
#pragma unroll
  for (int c = 0; c < 8; c++) {
    bf16x8 ov;
#pragma unroll
    for (int j = 0; j < 8; j++) ov[j] = (bf16)(o[c * 8 + j] * inv);
    *(bf16x8*)(Or + c * 8) = ov;
  }
}

// ---------------------------------------------------------------------------
extern "C" void kernel_launch(void* const* d_in, const int* in_sizes, int n_in,
                              void* d_out, int out_size, void* d_ws, size_t ws_size,
                              hipStream_t stream) {
  const float* query = (const float*)d_in[0];
  const float* key   = (const float*)d_in[1];
  const float* value = (const float*)d_in[2];
  const float* Wq    = (const float*)d_in[3];
  const float* Wk    = (const float*)d_in[4];
  const float* Wv    = (const float*)d_in[5];
  const float* Wo    = (const float*)d_in[6];
  const float* bo    = (const float*)d_in[7];
  float* out = (float*)d_out;

  char* ws = (char*)d_ws;
  size_t off = 0;
  auto take = [&](size_t bytes) -> void* {
    void* p = ws + off;
    off += (bytes + 255) & ~(size_t)255;
    return p;
  };
  const size_t WB = (size_t)1024 * 1024 * 2;   // 2.10 MB
  bf16* wqx = (bf16*)take(WB);
  bf16* wkx = (bf16*)take(WB);
  bf16* wvx = (bf16*)take(WB);
  bf16* wox = (bf16*)take(WB);
  bf16* Qb  = (bf16*)take((size_t)32 * L_SEQ * 64 * 2);   // 16.78 MB
  bf16* fK  = (bf16*)take((size_t)32 * NFLAT * 64 * 2);   // 33.55 MB
  bf16* fV  = (bf16*)take((size_t)32 * NFLAT * 64 * 2);   // 33.55 MB
  bf16* Ob  = (bf16*)take((size_t)8192 * 1024 * 2);       // 16.78 MB
  (void)in_sizes; (void)n_in; (void)out_size; (void)ws_size;

  // 1. weights fp32 -> bf16
  cvtw_kernel<<<256, 256, 0, stream>>>(Wq, Wk, Wv, Wo, wqx, wkx, wvx, wox);

  // 2. Q/K/V projections reading f32 activations directly + tree levels 1..6
  gemmf_qkv_kernel<<<dim3(512, 3), 256, 0, stream>>>(
      query, key, value, wqx, wkx, wvx, Qb, fK, fV);

  // 3. tree levels 7..12
  tree_l712<<<32, 64, 0, stream>>>(fK, fV);

  // 4. sparse attention
  attn_kernel<<<dim3(64, 32), 64, 0, stream>>>(Qb, fK, fV, Ob);

  // 5. output projection
  gemm8_out_kernel<<<512, 256, 0, stream>>>(Ob, wox, bo, out);
}